// Round 2
// baseline (637.506 us; speedup 1.0000x reference)
//
#include <hip/hip_runtime.h>
#include <hip/hip_bf16.h>
#include <stdint.h>

#define L_ 25
#define E_ 64
#define H_ 8
#define B_ 1000
#define S_ 512
#define G_ 4                      // batch elements per block (recurrent kernel)
#define TPB_REC (L_ * G_ * H_)    // 800 threads
#define NDIAG (S_ + L_ - 1)       // 536 pipeline diagonals

__device__ __forceinline__ float ulo(uint32_t u) { return __uint_as_float(u << 16); }
__device__ __forceinline__ float uhi(uint32_t u) { return __uint_as_float(u & 0xffff0000u); }

__device__ __forceinline__ float toF(float v) { return v; }
__device__ __forceinline__ float toF(__hip_bfloat16 v) { return __bfloat162float(v); }
__device__ __forceinline__ void stP(float* p, float v) { *p = v; }
__device__ __forceinline__ void stP(__hip_bfloat16* p, float v) { *p = __float2bfloat16(v); }

// load 8 consecutive elements as fp32 (16B-aligned for bf16, 32B for f32)
__device__ __forceinline__ void load8f(const __hip_bfloat16* p, float* o) {
  const uint4 v = *(const uint4*)p;
  o[0] = ulo(v.x); o[1] = uhi(v.x); o[2] = ulo(v.y); o[3] = uhi(v.y);
  o[4] = ulo(v.z); o[5] = uhi(v.z); o[6] = ulo(v.w); o[7] = uhi(v.w);
}
__device__ __forceinline__ void load8f(const float* p, float* o) {
  const float4 a = ((const float4*)p)[0];
  const float4 b = ((const float4*)p)[1];
  o[0] = a.x; o[1] = a.y; o[2] = a.z; o[3] = a.w;
  o[4] = b.x; o[5] = b.y; o[6] = b.z; o[7] = b.w;
}

__device__ __forceinline__ float sigmo(float x) {
  x = fminf(fmaxf(x, -30.f), 30.f);
  return 1.f / (1.f + __expf(-x));
}
__device__ __forceinline__ float tanh_(float x) {
  x = fminf(fmaxf(x, -15.f), 15.f);
  const float e = __expf(-2.f * x);
  return (1.f - e) / (1.f + e);
}

// ---------------------------------------------------------------------------
// Kernel 0: dtype probe. If the embedding's raw u16s, read as bf16, contain a
// magnitude > 2.0, the data must be fp32 (random mantissa bits) -> mode 0.
// Otherwise genuine bf16 (|w| <= ~0.5) -> mode 1.
// ---------------------------------------------------------------------------
__global__ void gru_detect(const unsigned short* __restrict__ u16, int* __restrict__ flag) {
  const int i = threadIdx.x;  // 64 threads
  float m = 0.f;
#pragma unroll
  for (int k = 0; k < 4; ++k) {
    const uint32_t u = u16[i * 4 + k];
    float v = fabsf(__uint_as_float(u << 16));
    if (!(v < 1e30f)) v = 1e30f;  // NaN/Inf -> large
    m = fmaxf(m, v);
  }
#pragma unroll
  for (int off = 32; off; off >>= 1) m = fmaxf(m, __shfl_down(m, off, 64));
  if (i == 0) *flag = (m > 2.0f) ? 0 : 1;  // 0 = fp32 inputs, 1 = bf16 inputs
}

// ---------------------------------------------------------------------------
// Kernel 1: precompute layer-0 x-projections: pre[(b*S+t)*24 + gate*8 + j]
// ---------------------------------------------------------------------------
template <typename T, typename PT>
__global__ __launch_bounds__(256) void gru_pre(
    const int* __restrict__ flag, int want,
    const int* __restrict__ x, const T* __restrict__ emb,
    const T* __restrict__ Wz, const T* __restrict__ Wr,
    const T* __restrict__ Wh, PT* __restrict__ pre) {
  if (*flag != want) return;
  const int Tg = blockIdx.x * 256 + threadIdx.x;
  const int gate = Tg % 3;
  const int chunk = Tg / 3;  // < 128000
  const T* W = (gate == 0) ? Wz : ((gate == 1) ? Wr : Wh);
  const int pos0 = chunk * 4;

  const int4 t4 = *(const int4*)(x + pos0);
  const int tok[4] = {t4.x, t4.y, t4.z, t4.w};

  float acc[4][8];
#pragma unroll
  for (int p = 0; p < 4; ++p)
#pragma unroll
    for (int jj = 0; jj < 8; ++jj) acc[p][jj] = 0.f;

  for (int kb = 0; kb < 8; ++kb) {  // K = 64 in blocks of 8
    float wf[64];
#pragma unroll
    for (int i = 0; i < 8; ++i) load8f(W + kb * 64 + i * 8, wf + 8 * i);
#pragma unroll
    for (int p = 0; p < 4; ++p) {
      float ef[8];
      load8f(emb + (size_t)tok[p] * E_ + kb * 8, ef);
#pragma unroll
      for (int kk = 0; kk < 8; ++kk)
#pragma unroll
        for (int jj = 0; jj < 8; ++jj)
          acc[p][jj] = fmaf(ef[kk], wf[8 * kk + jj], acc[p][jj]);
    }
  }
#pragma unroll
  for (int p = 0; p < 4; ++p) {
    PT* o = pre + (size_t)(pos0 + p) * 24 + gate * 8;
#pragma unroll
    for (int jj = 0; jj < 8; ++jj) stP(o + jj, acc[p][jj]);
  }
}

// ---------------------------------------------------------------------------
// Kernel 2: pipelined recurrence. Block = 25 layers x G batches x 8 hidden.
// Diagonal d: layer l computes timestep t = d - l. Weights in registers.
// ---------------------------------------------------------------------------
template <typename T, typename PT>
__global__ __launch_bounds__(TPB_REC) void gru_rec(
    const int* __restrict__ flag, int want,
    const PT* __restrict__ pre,
    const T* __restrict__ Whz0, const T* __restrict__ bz0,
    const T* __restrict__ Whr0, const T* __restrict__ br0,
    const T* __restrict__ WrH0, const T* __restrict__ bH0,
    const T* __restrict__ Wxz, const T* __restrict__ Whz,
    const T* __restrict__ bz, const T* __restrict__ Wxr,
    const T* __restrict__ Whr, const T* __restrict__ br,
    const T* __restrict__ WxH, const T* __restrict__ WrH,
    const T* __restrict__ bH, const T* __restrict__ Why,
    const T* __restrict__ by, T* __restrict__ out) {
  if (*flag != want) return;
  __shared__ float hbuf[2 * TPB_REC];  // ping-pong h state [l][g][j]
  __shared__ float hrbuf[TPB_REC];     // per-group (h*r) scratch

  const int tid = threadIdx.x;
  const int l = tid >> 5;        // / (G_*H_) = 32
  const int g = (tid >> 3) & 3;  // batch slot
  const int j = tid & 7;         // hidden index
  const int b = blockIdx.x * G_ + g;
  const int grp = tid & ~7;      // base of this 8-thread group (wave-contained)

  hbuf[tid] = 0.f;
  hbuf[TPB_REC + tid] = 0.f;

  // ---- this thread's weight columns into registers (fp32) ----
  float wxz[8], whz[8], wxr[8], whr[8], wxh[8], wrh[8];
  float vbz, vbr, vbh;
  if (l == 0) {
#pragma unroll
    for (int k = 0; k < 8; ++k) {
      whz[k] = toF(Whz0[k * 8 + j]);
      whr[k] = toF(Whr0[k * 8 + j]);
      wrh[k] = toF(WrH0[k * 8 + j]);
      wxz[k] = 0.f; wxr[k] = 0.f; wxh[k] = 0.f;
    }
    vbz = toF(bz0[j]); vbr = toF(br0[j]); vbh = toF(bH0[j]);
  } else {
    const int base = (l - 1) * 64;
#pragma unroll
    for (int k = 0; k < 8; ++k) {
      wxz[k] = toF(Wxz[base + k * 8 + j]);
      whz[k] = toF(Whz[base + k * 8 + j]);
      wxr[k] = toF(Wxr[base + k * 8 + j]);
      whr[k] = toF(Whr[base + k * 8 + j]);
      wxh[k] = toF(WxH[base + k * 8 + j]);
      wrh[k] = toF(WrH[base + k * 8 + j]);
    }
    vbz = toF(bz[(l - 1) * 8 + j]);
    vbr = toF(br[(l - 1) * 8 + j]);
    vbh = toF(bH[(l - 1) * 8 + j]);
  }

  // layer-0 precomputed x-projection, double-buffered in registers
  int pb = 0;
  float preZ = 0.f, preR = 0.f, preH = 0.f;
  if (l == 0) {
    pb = b * (S_ * 24);
    preZ = toF(pre[pb + j]);
    preR = toF(pre[pb + 8 + j]);
    preH = toF(pre[pb + 16 + j]);
  }

  __syncthreads();

  for (int d = 0; d < NDIAG; ++d) {
    const float* prevb = hbuf + (d & 1) * TPB_REC;
    float* curb = hbuf + ((~d) & 1) * TPB_REC;
    const int t = d - l;
    const float own = prevb[tid];
    float hnew = own;
    if (t >= 0 && t < S_) {
      float hv[8];
#pragma unroll
      for (int k = 0; k < 8; ++k) hv[k] = prevb[grp + k];

      float az = vbz, ar = vbr, ah = vbh;
      if (l == 0) {
        az += preZ; ar += preR; ah += preH;
        if (t + 1 < S_) {  // prefetch next timestep
          const int o = pb + (t + 1) * 24;
          preZ = toF(pre[o + j]);
          preR = toF(pre[o + 8 + j]);
          preH = toF(pre[o + 16 + j]);
        }
      } else {
#pragma unroll
        for (int k = 0; k < 8; ++k) {
          const float xv = prevb[grp - G_ * H_ + k];  // layer l-1 output at t
          az = fmaf(xv, wxz[k], az);
          ar = fmaf(xv, wxr[k], ar);
          ah = fmaf(xv, wxh[k], ah);
        }
      }
#pragma unroll
      for (int k = 0; k < 8; ++k) {
        az = fmaf(hv[k], whz[k], az);
        ar = fmaf(hv[k], whr[k], ar);
      }
      const float z = sigmo(az);
      const float r = sigmo(ar);

      hrbuf[tid] = own * r;             // share (h*r) within 8-thread group
      __builtin_amdgcn_wave_barrier();  // group is wave-contained
#pragma unroll
      for (int k = 0; k < 8; ++k) ah = fmaf(hrbuf[grp + k], wrh[k], ah);

      const float Hc = tanh_(ah);
      hnew = fmaf(z, Hc - own, own);    // h*(1-z) + z*Hc
    }
    curb[tid] = hnew;
    __syncthreads();
  }

  // ---- epilogue: h_last and logits ----
  const float* fin = hbuf + (NDIAG & 1) * TPB_REC;
  stP(out + B_ + (l * B_ + b) * H_ + j, fin[tid]);
  if (l == L_ - 1 && j == 0) {
    float s = toF(by[0]);
#pragma unroll
    for (int k = 0; k < 8; ++k)
      s = fmaf(fin[((L_ - 1) * G_ + g) * 8 + k], toF(Why[k]), s);
    stP(out + b, s);
  }
}

// ---------------------------------------------------------------------------
template <typename T, typename PT>
static void launch_mode(const int* flag, int want, void* const* d_in, PT* pre,
                        T* out, hipStream_t stream) {
  const int* x = (const int*)d_in[0];
  const T* emb = (const T*)d_in[1];
  const T* Wxz0 = (const T*)d_in[2];
  const T* Whz0 = (const T*)d_in[3];
  const T* bz0 = (const T*)d_in[4];
  const T* Wxr0 = (const T*)d_in[5];
  const T* Whr0 = (const T*)d_in[6];
  const T* br0 = (const T*)d_in[7];
  const T* WxH0 = (const T*)d_in[8];
  const T* WrH0 = (const T*)d_in[9];
  const T* bH0 = (const T*)d_in[10];
  const T* Wxz = (const T*)d_in[11];
  const T* Whz = (const T*)d_in[12];
  const T* bz = (const T*)d_in[13];
  const T* Wxr = (const T*)d_in[14];
  const T* Whr = (const T*)d_in[15];
  const T* br = (const T*)d_in[16];
  const T* WxH = (const T*)d_in[17];
  const T* WrH = (const T*)d_in[18];
  const T* bH = (const T*)d_in[19];
  const T* Why = (const T*)d_in[20];
  const T* by = (const T*)d_in[21];

  const int preBlocks = (3 * (B_ * S_ / 4)) / 256;  // 1500, exact
  gru_pre<T, PT><<<preBlocks, 256, 0, stream>>>(flag, want, x, emb, Wxz0, Wxr0, WxH0, pre);
  gru_rec<T, PT><<<B_ / G_, TPB_REC, 0, stream>>>(
      flag, want, pre, Whz0, bz0, Whr0, br0, WrH0, bH0, Wxz, Whz, bz, Wxr, Whr,
      br, WxH, WrH, bH, Why, by, out);
}

extern "C" void kernel_launch(void* const* d_in, const int* in_sizes, int n_in,
                              void* d_out, int out_size, void* d_ws, size_t ws_size,
                              hipStream_t stream) {
  int* flag = (int*)d_ws;
  char* preMem = (char*)d_ws + 256;
  const size_t needF = (size_t)B_ * S_ * 24 * sizeof(float) + 256;

  gru_detect<<<1, 64, 0, stream>>>((const unsigned short*)d_in[1], flag);

  if (ws_size >= needF) {
    float* pre = (float*)preMem;
    launch_mode<float, float>(flag, 0, d_in, pre, (float*)d_out, stream);
    launch_mode<__hip_bfloat16, float>(flag, 1, d_in, pre, (__hip_bfloat16*)d_out, stream);
  } else {  // small workspace: bf16 pre buffer (24.6 MB)
    __hip_bfloat16* pre = (__hip_bfloat16*)preMem;
    launch_mode<float, __hip_bfloat16>(flag, 0, d_in, pre, (float*)d_out, stream);
    launch_mode<__hip_bfloat16, __hip_bfloat16>(flag, 1, d_in, pre, (__hip_bfloat16*)d_out, stream);
  }
}